// Round 3
// baseline (1052.387 us; speedup 1.0000x reference)
//
#include <hip/hip_runtime.h>
#include <hip/hip_bf16.h>

#define N_NODES 50000
#define N_EDGES 800000
#define DIM_IN 64
#define DIM_H 32
#define HEADS 4
#define NCLS 10
#define NEG 0.2f

#define FMA4(acc, s, w) \
    { acc.x += (s) * (w).x; acc.y += (s) * (w).y; acc.z += (s) * (w).z; acc.w += (s) * (w).w; }

// ---------------- CSR build ----------------

__global__ void k_hist(const int* __restrict__ dst, int* __restrict__ deg) {
    int e = blockIdx.x * 256 + threadIdx.x;
    if (e < N_EDGES) atomicAdd(&deg[dst[e]], 1);
}

__global__ void k_scan_block(const int* __restrict__ deg, int* __restrict__ row,
                             int* __restrict__ bsums) {
    __shared__ int s[256];
    int i = blockIdx.x * 256 + threadIdx.x;
    int v = (i < N_NODES) ? deg[i] : 0;
    s[threadIdx.x] = v;
    __syncthreads();
    for (int off = 1; off < 256; off <<= 1) {
        int t = (threadIdx.x >= off) ? s[threadIdx.x - off] : 0;
        __syncthreads();
        s[threadIdx.x] += t;
        __syncthreads();
    }
    if (i < N_NODES) row[i] = s[threadIdx.x] - v;  // exclusive
    if (threadIdx.x == 255) bsums[blockIdx.x] = s[255];
}

__global__ void k_scan_sums(int* __restrict__ bsums, int nb) {
    __shared__ int s[256];
    int v = (threadIdx.x < nb) ? bsums[threadIdx.x] : 0;
    s[threadIdx.x] = v;
    __syncthreads();
    for (int off = 1; off < 256; off <<= 1) {
        int t = (threadIdx.x >= off) ? s[threadIdx.x - off] : 0;
        __syncthreads();
        s[threadIdx.x] += t;
        __syncthreads();
    }
    if (threadIdx.x < nb) bsums[threadIdx.x] = s[threadIdx.x] - v;  // exclusive
}

__global__ void k_scan_add(int* __restrict__ row, int* __restrict__ cursor,
                           const int* __restrict__ bsums) {
    int i = blockIdx.x * 256 + threadIdx.x;
    if (i < N_NODES) {
        int r = row[i] + bsums[blockIdx.x];
        row[i] = r;
        cursor[i] = r;
    }
    if (i == 0) row[N_NODES] = N_EDGES;
}

__global__ void k_scatter(const int* __restrict__ dst, const int* __restrict__ srcarr,
                          int* __restrict__ cursor, int* __restrict__ adj) {
    int e = blockIdx.x * 256 + threadIdx.x;
    if (e < N_EDGES) {
        int d = dst[e];
        int s = srcarr[e];
        int p = atomicAdd(&cursor[d], 1);
        adj[p] = s;
    }
}

// ---------------- dense (register-tiled f32 GEMMs) ----------------

// x = gf @ W_in + b_in.  [50000x64]@[64x32].
// Block: 256 threads, 128 nodes. Thread: 4 nodes x 4 cols tile.
// cg = t&7 (col group, c=cg*4), ng = t>>3 (node group, nn=ng*4).
__global__ void k_embed(const float* __restrict__ gf, const float* __restrict__ W,
                        const float* __restrict__ b, float* __restrict__ x) {
    __shared__ float Ws[DIM_IN * DIM_H];  // 8 KB, W[k][c]
    __shared__ float Xt[DIM_IN * 132];    // ~33 KB, transposed inputs, pad 132
    int t = threadIdx.x;
    for (int i = t; i < DIM_IN * DIM_H; i += 256) Ws[i] = W[i];
    int nb = blockIdx.x * 128;
    for (int i = t; i < 128 * DIM_IN; i += 256) {
        int nn = i >> 6, k = i & 63;
        int n = nb + nn;
        Xt[k * 132 + nn] = (n < N_NODES) ? gf[(size_t)n * DIM_IN + k] : 0.f;
    }
    __syncthreads();
    int cg = t & 7, ng = t >> 3;
    float4 bias = ((const float4*)b)[cg];
    float4 a0 = bias, a1 = bias, a2 = bias, a3 = bias;
#pragma unroll
    for (int k = 0; k < DIM_IN; k++) {
        float4 w = *(const float4*)&Ws[k * DIM_H + cg * 4];
        float4 xv = *(const float4*)&Xt[k * 132 + ng * 4];
        FMA4(a0, xv.x, w);
        FMA4(a1, xv.y, w);
        FMA4(a2, xv.z, w);
        FMA4(a3, xv.w, w);
    }
    int n0 = nb + ng * 4;
    if (n0 + 0 < N_NODES) *(float4*)&x[(size_t)(n0 + 0) * DIM_H + cg * 4] = a0;
    if (n0 + 1 < N_NODES) *(float4*)&x[(size_t)(n0 + 1) * DIM_H + cg * 4] = a1;
    if (n0 + 2 < N_NODES) *(float4*)&x[(size_t)(n0 + 2) * DIM_H + cg * 4] = a2;
    if (n0 + 3 < N_NODES) *(float4*)&x[(size_t)(n0 + 3) * DIM_H + cg * 4] = a3;
}

// fs|fd = x @ [Wsrc|Wdst] + [bsrc|bdst].  [50000x32]@[32x256].
// Block: 256 threads, 64 nodes (4 passes of 16). Thread: 4 nodes x 4 cols.
// cg = t&63 (c=cg*4; cg<32 -> fs, else fd), ng = t>>6 (nn=ng*4).
__global__ void k_proj(const float* __restrict__ x, const float* __restrict__ Wsrc,
                       const float* __restrict__ bsrc, const float* __restrict__ Wdst,
                       const float* __restrict__ bdst, float* __restrict__ fs,
                       float* __restrict__ fd) {
    __shared__ float Ws[DIM_H * 256];  // 32 KB, [k][c] with c in [0,256)
    __shared__ float Xt[DIM_H * 20];   // 2.5 KB, [k][nn] pad 20
    int t = threadIdx.x;
    for (int i = t; i < DIM_H * 128; i += 256) {
        int k = i >> 7, c = i & 127;
        Ws[k * 256 + c] = Wsrc[i];
        Ws[k * 256 + 128 + c] = Wdst[i];
    }
    int cg = t & 63, ng = t >> 6;
    float4 bias = (cg < 32) ? ((const float4*)bsrc)[cg] : ((const float4*)bdst)[cg - 32];
    float* outp = (cg < 32) ? fs : fd;
    int c = (cg & 31) * 4;
    int nodeBase = blockIdx.x * 64;
    for (int p = 0; p < 4; ++p) {
        int nb = nodeBase + p * 16;
        __syncthreads();  // protect previous pass's Xt (and initial Ws staging)
        for (int i = t; i < 512; i += 256) {
            int nn = i >> 5, k = i & 31;
            int n = nb + nn;
            Xt[k * 20 + nn] = (n < N_NODES) ? x[(size_t)n * DIM_H + k] : 0.f;
        }
        __syncthreads();
        float4 a0 = bias, a1 = bias, a2 = bias, a3 = bias;
#pragma unroll
        for (int k = 0; k < DIM_H; k++) {
            float4 w = *(const float4*)&Ws[k * 256 + cg * 4];
            float4 xv = *(const float4*)&Xt[k * 20 + ng * 4];
            FMA4(a0, xv.x, w);
            FMA4(a1, xv.y, w);
            FMA4(a2, xv.z, w);
            FMA4(a3, xv.w, w);
        }
        int n0 = nb + ng * 4;
        if (n0 + 0 < N_NODES) *(float4*)&outp[(size_t)(n0 + 0) * 128 + c] = a0;
        if (n0 + 1 < N_NODES) *(float4*)&outp[(size_t)(n0 + 1) * 128 + c] = a1;
        if (n0 + 2 < N_NODES) *(float4*)&outp[(size_t)(n0 + 2) * 128 + c] = a2;
        if (n0 + 3 < N_NODES) *(float4*)&outp[(size_t)(n0 + 3) * 128 + c] = a3;
    }
}

// ---------------- GAT gather ----------------
// One wave per destination node. Lane l: head h=l>>4, float2 slot l of the
// 128-float row. Adjacency loaded lane-parallel and broadcast via shfl; 8
// independent fs-row loads in flight. Softmax shift dropped (shift-invariant;
// |logits| small). Epilogue fuses head-mean (+optional relu).
__device__ __forceinline__ void edge_acc(float2 f, float2 fdv, float2 a2,
                                         float2& acc, float& den) {
    float tx = f.x + fdv.x; tx = tx > 0.f ? tx : NEG * tx;
    float ty = f.y + fdv.y; ty = ty > 0.f ? ty : NEG * ty;
    float p = tx * a2.x + ty * a2.y;
    p += __shfl_xor(p, 1, 64);
    p += __shfl_xor(p, 2, 64);
    p += __shfl_xor(p, 4, 64);
    p += __shfl_xor(p, 8, 64);
    float w = __expf(p);
    den += w;
    acc.x += w * f.x;
    acc.y += w * f.y;
}

__global__ void k_gather(const float* __restrict__ fs, const float* __restrict__ fd,
                         const float* __restrict__ attn, const int* __restrict__ row,
                         const int* __restrict__ adj, float* __restrict__ xout,
                         int do_relu) {
    int wave = threadIdx.x >> 6;
    int lane = threadIdx.x & 63;
    int n = blockIdx.x * 4 + wave;
    if (n >= N_NODES) return;
    float2 a2 = ((const float2*)attn)[lane];
    float2 fdv = ((const float2*)(fd + (size_t)n * 128))[lane];
    const float2* fs2 = (const float2*)fs;
    float2 acc = {0.f, 0.f};
    float den = 0.f;
    int beg = row[n], end = row[n + 1];
    for (int base = beg; base < end; base += 64) {
        int m = end - base;
        if (m > 64) m = 64;
        int myadj = (lane < m) ? adj[base + lane] : 0;
        int j = 0;
        for (; j + 8 <= m; j += 8) {
            int s0 = __shfl(myadj, j + 0, 64);
            int s1 = __shfl(myadj, j + 1, 64);
            int s2 = __shfl(myadj, j + 2, 64);
            int s3 = __shfl(myadj, j + 3, 64);
            int s4 = __shfl(myadj, j + 4, 64);
            int s5 = __shfl(myadj, j + 5, 64);
            int s6 = __shfl(myadj, j + 6, 64);
            int s7 = __shfl(myadj, j + 7, 64);
            float2 f0 = fs2[(size_t)s0 * 64 + lane];
            float2 f1 = fs2[(size_t)s1 * 64 + lane];
            float2 f2 = fs2[(size_t)s2 * 64 + lane];
            float2 f3 = fs2[(size_t)s3 * 64 + lane];
            float2 f4 = fs2[(size_t)s4 * 64 + lane];
            float2 f5 = fs2[(size_t)s5 * 64 + lane];
            float2 f6 = fs2[(size_t)s6 * 64 + lane];
            float2 f7 = fs2[(size_t)s7 * 64 + lane];
            edge_acc(f0, fdv, a2, acc, den);
            edge_acc(f1, fdv, a2, acc, den);
            edge_acc(f2, fdv, a2, acc, den);
            edge_acc(f3, fdv, a2, acc, den);
            edge_acc(f4, fdv, a2, acc, den);
            edge_acc(f5, fdv, a2, acc, den);
            edge_acc(f6, fdv, a2, acc, den);
            edge_acc(f7, fdv, a2, acc, den);
        }
        for (; j < m; ++j) {
            int s = __shfl(myadj, j, 64);
            float2 f = fs2[(size_t)s * 64 + lane];
            edge_acc(f, fdv, a2, acc, den);
        }
    }
    float inv = den > 0.f ? 1.f / den : 0.f;
    float ox = acc.x * inv, oy = acc.y * inv;
    float vx = ox + __shfl_xor(ox, 16, 64);
    float vy = oy + __shfl_xor(oy, 16, 64);
    vx += __shfl_xor(vx, 32, 64);
    vy += __shfl_xor(vy, 32, 64);
    vx *= 0.25f;
    vy *= 0.25f;
    if (do_relu) {
        vx = vx > 0.f ? vx : 0.f;
        vy = vy > 0.f ? vy : 0.f;
    }
    if (lane < 16) ((float2*)(xout + (size_t)n * 32))[lane] = make_float2(vx, vy);
}

// sum x[n][32] over nodes -> partial[block][32]
__global__ void k_reduce(const float* __restrict__ x, float* __restrict__ partial) {
    int d = threadIdx.x & 31, g = threadIdx.x >> 5;
    float acc = 0.f;
    int stride = gridDim.x * 8;
    for (int n = blockIdx.x * 8 + g; n < N_NODES; n += stride) {
        acc += x[(size_t)n * 32 + d];
    }
    __shared__ float s[256];
    s[threadIdx.x] = acc;
    __syncthreads();
    for (int off = 128; off >= 32; off >>= 1) {
        if (threadIdx.x < off) s[threadIdx.x] += s[threadIdx.x + off];
        __syncthreads();
    }
    if (threadIdx.x < 32) partial[blockIdx.x * 32 + threadIdx.x] = s[threadIdx.x];
}

__global__ void k_final(const float* __restrict__ partial, const float* __restrict__ Wh1,
                        const float* __restrict__ bh1, const float* __restrict__ Wh2,
                        const float* __restrict__ bh2, float* __restrict__ out) {
    __shared__ float gv[32], gh[32], lg[16];
    int t = threadIdx.x;
    if (t < 32) {
        float s = 0.f;
        for (int b = 0; b < 256; b++) s += partial[b * 32 + t];
        gv[t] = s * (1.f / (float)N_NODES);
    }
    __syncthreads();
    if (t < 32) {
        float s = bh1[t];
        for (int d = 0; d < 32; d++) s += gv[d] * Wh1[d * 32 + t];
        gh[t] = s > 0.f ? s : 0.f;
    }
    __syncthreads();
    if (t < NCLS) {
        float s = bh2[t];
        for (int j = 0; j < 32; j++) s += gh[j] * Wh2[j * NCLS + t];
        lg[t] = s;
    }
    __syncthreads();
    if (t == 0) {
        float m = lg[0];
        for (int c = 1; c < NCLS; c++) m = fmaxf(m, lg[c]);
        float ex[NCLS], sum = 0.f;
        for (int c = 0; c < NCLS; c++) {
            ex[c] = __expf(lg[c] - m);
            sum += ex[c];
        }
        float inv = 1.f / sum;
        for (int c = 0; c < NCLS; c++) out[c] = ex[c] * inv;
    }
}

extern "C" void kernel_launch(void* const* d_in, const int* in_sizes, int n_in,
                              void* d_out, int out_size, void* d_ws, size_t ws_size,
                              hipStream_t stream) {
    const float* g_feats = (const float*)d_in[0];
    const int* edge_src = (const int*)d_in[1];
    const int* edge_dst = (const int*)d_in[2];
    const float* W_in = (const float*)d_in[3];
    const float* b_in = (const float*)d_in[4];
    const float* W1_src = (const float*)d_in[5];
    const float* b1_src = (const float*)d_in[6];
    const float* W1_dst = (const float*)d_in[7];
    const float* b1_dst = (const float*)d_in[8];
    const float* attn1 = (const float*)d_in[9];
    const float* W2_src = (const float*)d_in[10];
    const float* b2_src = (const float*)d_in[11];
    const float* W2_dst = (const float*)d_in[12];
    const float* b2_dst = (const float*)d_in[13];
    const float* attn2 = (const float*)d_in[14];
    const float* Wh1 = (const float*)d_in[15];
    const float* bh1 = (const float*)d_in[16];
    const float* Wh2 = (const float*)d_in[17];
    const float* bh2 = (const float*)d_in[18];

    // workspace layout
    float* x = (float*)d_ws;                      // N*32
    float* fs = x + (size_t)N_NODES * 32;         // N*128
    float* fd = fs + (size_t)N_NODES * 128;       // N*128
    float* partial = fd + (size_t)N_NODES * 128;  // 256*32
    int* deg = (int*)(partial + 256 * 32);        // N
    int* row = deg + N_NODES;                     // N+1
    int* cursor = row + N_NODES + 1;              // N
    int* adj = cursor + N_NODES;                  // E (src values, CSR order)
    int* bsums = adj + N_EDGES;                   // NB

    const int EB = (N_EDGES + 255) / 256;
    const int NB = (N_NODES + 255) / 256;  // 196

    hipMemsetAsync(deg, 0, N_NODES * sizeof(int), stream);
    k_hist<<<EB, 256, 0, stream>>>(edge_dst, deg);
    k_scan_block<<<NB, 256, 0, stream>>>(deg, row, bsums);
    k_scan_sums<<<1, 256, 0, stream>>>(bsums, NB);
    k_scan_add<<<NB, 256, 0, stream>>>(row, cursor, bsums);
    k_scatter<<<EB, 256, 0, stream>>>(edge_dst, edge_src, cursor, adj);

    k_embed<<<(N_NODES + 127) / 128, 256, 0, stream>>>(g_feats, W_in, b_in, x);

    // layer 1
    k_proj<<<(N_NODES + 63) / 64, 256, 0, stream>>>(x, W1_src, b1_src, W1_dst, b1_dst,
                                                    fs, fd);
    k_gather<<<(N_NODES + 3) / 4, 256, 0, stream>>>(fs, fd, attn1, row, adj, x, 1);

    // layer 2
    k_proj<<<(N_NODES + 63) / 64, 256, 0, stream>>>(x, W2_src, b2_src, W2_dst, b2_dst,
                                                    fs, fd);
    k_gather<<<(N_NODES + 3) / 4, 256, 0, stream>>>(fs, fd, attn2, row, adj, x, 0);

    k_reduce<<<256, 256, 0, stream>>>(x, partial);
    k_final<<<1, 256, 0, stream>>>(partial, Wh1, bh1, Wh2, bh2, (float*)d_out);
}

// Round 4
// 388.895 us; speedup vs baseline: 2.7061x; 2.7061x over previous
//
#include <hip/hip_runtime.h>
#include <hip/hip_bf16.h>

#define N_NODES 50000
#define N_EDGES 800000
#define DIM_IN 64
#define DIM_H 32
#define HEADS 4
#define NCLS 10
#define NEG 0.2f

// ---------------- CSR build ----------------

__global__ void k_hist(const int* __restrict__ dst, int* __restrict__ deg) {
    int e = blockIdx.x * 256 + threadIdx.x;
    if (e < N_EDGES) atomicAdd(&deg[dst[e]], 1);
}

__global__ void k_scan_block(const int* __restrict__ deg, int* __restrict__ row,
                             int* __restrict__ bsums) {
    __shared__ int s[256];
    int i = blockIdx.x * 256 + threadIdx.x;
    int v = (i < N_NODES) ? deg[i] : 0;
    s[threadIdx.x] = v;
    __syncthreads();
    for (int off = 1; off < 256; off <<= 1) {
        int t = (threadIdx.x >= off) ? s[threadIdx.x - off] : 0;
        __syncthreads();
        s[threadIdx.x] += t;
        __syncthreads();
    }
    if (i < N_NODES) row[i] = s[threadIdx.x] - v;  // exclusive
    if (threadIdx.x == 255) bsums[blockIdx.x] = s[255];
}

__global__ void k_scan_sums(int* __restrict__ bsums, int nb) {
    __shared__ int s[256];
    int v = (threadIdx.x < nb) ? bsums[threadIdx.x] : 0;
    s[threadIdx.x] = v;
    __syncthreads();
    for (int off = 1; off < 256; off <<= 1) {
        int t = (threadIdx.x >= off) ? s[threadIdx.x - off] : 0;
        __syncthreads();
        s[threadIdx.x] += t;
        __syncthreads();
    }
    if (threadIdx.x < nb) bsums[threadIdx.x] = s[threadIdx.x] - v;  // exclusive
}

__global__ void k_scan_add(int* __restrict__ row, int* __restrict__ cursor,
                           const int* __restrict__ bsums) {
    int i = blockIdx.x * 256 + threadIdx.x;
    if (i < N_NODES) {
        int r = row[i] + bsums[blockIdx.x];
        row[i] = r;
        cursor[i] = r;
    }
    if (i == 0) row[N_NODES] = N_EDGES;
}

__global__ void k_scatter(const int* __restrict__ dst, const int* __restrict__ srcarr,
                          int* __restrict__ cursor, int* __restrict__ adj) {
    int e = blockIdx.x * 256 + threadIdx.x;
    if (e < N_EDGES) {
        int d = dst[e];
        int s = srcarr[e];
        int p = atomicAdd(&cursor[d], 1);
        adj[p] = s;
    }
}

// ---------------- dense (weights-in-registers, no LDS) ----------------

// x = gf @ W_in + b_in.  [50000x64]@[64x32].
// One wave per 16 nodes. Lane l: col c=l&31, k-half h=l>>5 (k in [32h,32h+32)).
// W held in 32 VGPRs/lane; x-row loaded via wave-uniform pointer; half-sum
// combined with one shfl_xor(32); lanes 0..31 store 128B row.
__global__ void k_embed(const float* __restrict__ gf, const float* __restrict__ W,
                        const float* __restrict__ b, float* __restrict__ x) {
    int lane = threadIdx.x & 63;
    int wave = (blockIdx.x * 256 + threadIdx.x) >> 6;
    int c = lane & 31, h = lane >> 5;
    float w[32];
#pragma unroll
    for (int k = 0; k < 32; k++) w[k] = W[(h * 32 + k) * DIM_H + c];
    float bc = b[c];
    int n0 = wave * 16;
#pragma unroll 1
    for (int i = 0; i < 16; i++) {
        int n = n0 + i;
        if (n >= N_NODES) break;
        int nu = __builtin_amdgcn_readfirstlane(n);
        const float4* xr = (const float4*)(gf + (size_t)nu * DIM_IN + h * 32);
        float acc = 0.f;
#pragma unroll
        for (int k4 = 0; k4 < 8; k4++) {
            float4 xv = xr[k4];
            acc += xv.x * w[k4 * 4 + 0];
            acc += xv.y * w[k4 * 4 + 1];
            acc += xv.z * w[k4 * 4 + 2];
            acc += xv.w * w[k4 * 4 + 3];
        }
        acc += __shfl_xor(acc, 32, 64);
        if (lane < 32) x[(size_t)nu * DIM_H + c] = acc + bc;
    }
}

// ff[n][0:128]=fs(n), ff[n][128:256]=fd(n).  [50000x32]@[32x256].
// One wave per 16 nodes. Lane l owns output cols 4l..4l+3; W[:,4l..4l+3] in
// 32 float4 registers (static index, fully unrolled). x-row via wave-uniform
// scalar loads. Store: 64 lanes x 16B = one contiguous 1KB segment.
__global__ void k_proj(const float* __restrict__ x, const float* __restrict__ Wsrc,
                       const float* __restrict__ bsrc, const float* __restrict__ Wdst,
                       const float* __restrict__ bdst, float* __restrict__ ff) {
    int lane = threadIdx.x & 63;
    int wave = (blockIdx.x * 256 + threadIdx.x) >> 6;
    int cl = lane & 31;
    const float4* Wb = (lane < 32) ? (const float4*)Wsrc : (const float4*)Wdst;
    const float4* bb = (lane < 32) ? (const float4*)bsrc : (const float4*)bdst;
    float4 w[32];
#pragma unroll
    for (int k = 0; k < 32; k++) w[k] = Wb[k * 32 + cl];
    float4 bias = bb[cl];
    int n0 = wave * 16;
#pragma unroll 1
    for (int i = 0; i < 16; i++) {
        int n = n0 + i;
        if (n >= N_NODES) break;
        int nu = __builtin_amdgcn_readfirstlane(n);
        const float4* xr = (const float4*)(x + (size_t)nu * DIM_H);
        float4 acc = bias;
#pragma unroll
        for (int k4 = 0; k4 < 8; k4++) {
            float4 xv = xr[k4];
#pragma unroll
            for (int j = 0; j < 4; j++) {
                float xk = (j == 0) ? xv.x : (j == 1) ? xv.y : (j == 2) ? xv.z : xv.w;
                float4 wk = w[k4 * 4 + j];
                acc.x += xk * wk.x;
                acc.y += xk * wk.y;
                acc.z += xk * wk.z;
                acc.w += xk * wk.w;
            }
        }
        *(float4*)&ff[(size_t)nu * 256 + lane * 4] = acc;
    }
}

// ---------------- GAT gather ----------------
// One wave per destination node. Lane l: head h=l>>4, float2 slot l of the
// 128-float fs part. ff row: [fs(128) | fd(128)]. Adjacency lane-parallel +
// shfl broadcast; 8 independent neighbor-row loads in flight. Softmax shift
// dropped (shift-invariant; |logits| small). Epilogue fuses head-mean.
__device__ __forceinline__ void edge_acc(float2 f, float2 fdv, float2 a2,
                                         float2& acc, float& den) {
    float tx = f.x + fdv.x; tx = tx > 0.f ? tx : NEG * tx;
    float ty = f.y + fdv.y; ty = ty > 0.f ? ty : NEG * ty;
    float p = tx * a2.x + ty * a2.y;
    p += __shfl_xor(p, 1, 64);
    p += __shfl_xor(p, 2, 64);
    p += __shfl_xor(p, 4, 64);
    p += __shfl_xor(p, 8, 64);
    float w = __expf(p);
    den += w;
    acc.x += w * f.x;
    acc.y += w * f.y;
}

__global__ void k_gather(const float* __restrict__ ff, const float* __restrict__ attn,
                         const int* __restrict__ row, const int* __restrict__ adj,
                         float* __restrict__ xout, int do_relu) {
    int wave = threadIdx.x >> 6;
    int lane = threadIdx.x & 63;
    int n = blockIdx.x * 4 + wave;
    if (n >= N_NODES) return;
    float2 a2 = ((const float2*)attn)[lane];
    const float2* ff2 = (const float2*)ff;
    float2 fdv = ff2[(size_t)n * 128 + 64 + lane];
    float2 acc = {0.f, 0.f};
    float den = 0.f;
    int beg = row[n], end = row[n + 1];
    for (int base = beg; base < end; base += 64) {
        int m = end - base;
        if (m > 64) m = 64;
        int myadj = (lane < m) ? adj[base + lane] : 0;
        int j = 0;
        for (; j + 8 <= m; j += 8) {
            int s0 = __shfl(myadj, j + 0, 64);
            int s1 = __shfl(myadj, j + 1, 64);
            int s2 = __shfl(myadj, j + 2, 64);
            int s3 = __shfl(myadj, j + 3, 64);
            int s4 = __shfl(myadj, j + 4, 64);
            int s5 = __shfl(myadj, j + 5, 64);
            int s6 = __shfl(myadj, j + 6, 64);
            int s7 = __shfl(myadj, j + 7, 64);
            float2 f0 = ff2[(size_t)s0 * 128 + lane];
            float2 f1 = ff2[(size_t)s1 * 128 + lane];
            float2 f2 = ff2[(size_t)s2 * 128 + lane];
            float2 f3 = ff2[(size_t)s3 * 128 + lane];
            float2 f4 = ff2[(size_t)s4 * 128 + lane];
            float2 f5 = ff2[(size_t)s5 * 128 + lane];
            float2 f6 = ff2[(size_t)s6 * 128 + lane];
            float2 f7 = ff2[(size_t)s7 * 128 + lane];
            edge_acc(f0, fdv, a2, acc, den);
            edge_acc(f1, fdv, a2, acc, den);
            edge_acc(f2, fdv, a2, acc, den);
            edge_acc(f3, fdv, a2, acc, den);
            edge_acc(f4, fdv, a2, acc, den);
            edge_acc(f5, fdv, a2, acc, den);
            edge_acc(f6, fdv, a2, acc, den);
            edge_acc(f7, fdv, a2, acc, den);
        }
        for (; j < m; ++j) {
            int s = __shfl(myadj, j, 64);
            float2 f = ff2[(size_t)s * 128 + lane];
            edge_acc(f, fdv, a2, acc, den);
        }
    }
    float inv = den > 0.f ? 1.f / den : 0.f;
    float ox = acc.x * inv, oy = acc.y * inv;
    float vx = ox + __shfl_xor(ox, 16, 64);
    float vy = oy + __shfl_xor(oy, 16, 64);
    vx += __shfl_xor(vx, 32, 64);
    vy += __shfl_xor(vy, 32, 64);
    vx *= 0.25f;
    vy *= 0.25f;
    if (do_relu) {
        vx = vx > 0.f ? vx : 0.f;
        vy = vy > 0.f ? vy : 0.f;
    }
    if (lane < 16) ((float2*)(xout + (size_t)n * 32))[lane] = make_float2(vx, vy);
}

// sum x[n][32] over nodes -> partial[block][32]
__global__ void k_reduce(const float* __restrict__ x, float* __restrict__ partial) {
    int d = threadIdx.x & 31, g = threadIdx.x >> 5;
    float acc = 0.f;
    int stride = gridDim.x * 8;
    for (int n = blockIdx.x * 8 + g; n < N_NODES; n += stride) {
        acc += x[(size_t)n * 32 + d];
    }
    __shared__ float s[256];
    s[threadIdx.x] = acc;
    __syncthreads();
    for (int off = 128; off >= 32; off >>= 1) {
        if (threadIdx.x < off) s[threadIdx.x] += s[threadIdx.x + off];
        __syncthreads();
    }
    if (threadIdx.x < 32) partial[blockIdx.x * 32 + threadIdx.x] = s[threadIdx.x];
}

__global__ void k_final(const float* __restrict__ partial, const float* __restrict__ Wh1,
                        const float* __restrict__ bh1, const float* __restrict__ Wh2,
                        const float* __restrict__ bh2, float* __restrict__ out) {
    __shared__ float gv[32], gh[32], lg[16];
    int t = threadIdx.x;
    if (t < 32) {
        float s = 0.f;
        for (int b = 0; b < 256; b++) s += partial[b * 32 + t];
        gv[t] = s * (1.f / (float)N_NODES);
    }
    __syncthreads();
    if (t < 32) {
        float s = bh1[t];
        for (int d = 0; d < 32; d++) s += gv[d] * Wh1[d * 32 + t];
        gh[t] = s > 0.f ? s : 0.f;
    }
    __syncthreads();
    if (t < NCLS) {
        float s = bh2[t];
        for (int j = 0; j < 32; j++) s += gh[j] * Wh2[j * NCLS + t];
        lg[t] = s;
    }
    __syncthreads();
    if (t == 0) {
        float m = lg[0];
        for (int c = 1; c < NCLS; c++) m = fmaxf(m, lg[c]);
        float ex[NCLS], sum = 0.f;
        for (int c = 0; c < NCLS; c++) {
            ex[c] = __expf(lg[c] - m);
            sum += ex[c];
        }
        float inv = 1.f / sum;
        for (int c = 0; c < NCLS; c++) out[c] = ex[c] * inv;
    }
}

extern "C" void kernel_launch(void* const* d_in, const int* in_sizes, int n_in,
                              void* d_out, int out_size, void* d_ws, size_t ws_size,
                              hipStream_t stream) {
    const float* g_feats = (const float*)d_in[0];
    const int* edge_src = (const int*)d_in[1];
    const int* edge_dst = (const int*)d_in[2];
    const float* W_in = (const float*)d_in[3];
    const float* b_in = (const float*)d_in[4];
    const float* W1_src = (const float*)d_in[5];
    const float* b1_src = (const float*)d_in[6];
    const float* W1_dst = (const float*)d_in[7];
    const float* b1_dst = (const float*)d_in[8];
    const float* attn1 = (const float*)d_in[9];
    const float* W2_src = (const float*)d_in[10];
    const float* b2_src = (const float*)d_in[11];
    const float* W2_dst = (const float*)d_in[12];
    const float* b2_dst = (const float*)d_in[13];
    const float* attn2 = (const float*)d_in[14];
    const float* Wh1 = (const float*)d_in[15];
    const float* bh1 = (const float*)d_in[16];
    const float* Wh2 = (const float*)d_in[17];
    const float* bh2 = (const float*)d_in[18];

    // workspace layout
    float* x = (float*)d_ws;                      // N*32
    float* ff = x + (size_t)N_NODES * 32;         // N*256 (fs|fd interleaved)
    float* partial = ff + (size_t)N_NODES * 256;  // 256*32
    int* deg = (int*)(partial + 256 * 32);        // N
    int* row = deg + N_NODES;                     // N+1
    int* cursor = row + N_NODES + 1;              // N
    int* adj = cursor + N_NODES;                  // E (src values, CSR order)
    int* bsums = adj + N_EDGES;                   // NB

    const int EB = (N_EDGES + 255) / 256;
    const int NB = (N_NODES + 255) / 256;  // 196
    const int WB = (N_NODES + 63) / 64;    // 782: 4 waves/block x 16 nodes/wave

    hipMemsetAsync(deg, 0, N_NODES * sizeof(int), stream);
    k_hist<<<EB, 256, 0, stream>>>(edge_dst, deg);
    k_scan_block<<<NB, 256, 0, stream>>>(deg, row, bsums);
    k_scan_sums<<<1, 256, 0, stream>>>(bsums, NB);
    k_scan_add<<<NB, 256, 0, stream>>>(row, cursor, bsums);
    k_scatter<<<EB, 256, 0, stream>>>(edge_dst, edge_src, cursor, adj);

    k_embed<<<WB, 256, 0, stream>>>(g_feats, W_in, b_in, x);

    // layer 1
    k_proj<<<WB, 256, 0, stream>>>(x, W1_src, b1_src, W1_dst, b1_dst, ff);
    k_gather<<<(N_NODES + 3) / 4, 256, 0, stream>>>(ff, attn1, row, adj, x, 1);

    // layer 2
    k_proj<<<WB, 256, 0, stream>>>(x, W2_src, b2_src, W2_dst, b2_dst, ff);
    k_gather<<<(N_NODES + 3) / 4, 256, 0, stream>>>(ff, attn2, row, adj, x, 0);

    k_reduce<<<256, 256, 0, stream>>>(x, partial);
    k_final<<<1, 256, 0, stream>>>(partial, Wh1, bh1, Wh2, bh2, (float*)d_out);
}

// Round 5
// 313.667 us; speedup vs baseline: 3.3551x; 1.2398x over previous
//
#include <hip/hip_runtime.h>
#include <hip/hip_bf16.h>

#define N_NODES 50000
#define N_EDGES 800000
#define DIM_IN 64
#define DIM_H 32
#define HEADS 4
#define NCLS 10
#define NEG 0.2f

// ---------------- CSR build ----------------

__global__ void k_hist(const int* __restrict__ dst, int* __restrict__ deg) {
    int e = blockIdx.x * 256 + threadIdx.x;
    if (e < N_EDGES) atomicAdd(&deg[dst[e]], 1);
}

__global__ void k_scan_block(const int* __restrict__ deg, int* __restrict__ row,
                             int* __restrict__ bsums) {
    __shared__ int s[256];
    int i = blockIdx.x * 256 + threadIdx.x;
    int v = (i < N_NODES) ? deg[i] : 0;
    s[threadIdx.x] = v;
    __syncthreads();
    for (int off = 1; off < 256; off <<= 1) {
        int t = (threadIdx.x >= off) ? s[threadIdx.x - off] : 0;
        __syncthreads();
        s[threadIdx.x] += t;
        __syncthreads();
    }
    if (i < N_NODES) row[i] = s[threadIdx.x] - v;  // exclusive
    if (threadIdx.x == 255) bsums[blockIdx.x] = s[255];
}

__global__ void k_scan_sums(int* __restrict__ bsums, int nb) {
    __shared__ int s[256];
    int v = (threadIdx.x < nb) ? bsums[threadIdx.x] : 0;
    s[threadIdx.x] = v;
    __syncthreads();
    for (int off = 1; off < 256; off <<= 1) {
        int t = (threadIdx.x >= off) ? s[threadIdx.x - off] : 0;
        __syncthreads();
        s[threadIdx.x] += t;
        __syncthreads();
    }
    if (threadIdx.x < nb) bsums[threadIdx.x] = s[threadIdx.x] - v;  // exclusive
}

__global__ void k_scan_add(int* __restrict__ row, int* __restrict__ cursor,
                           const int* __restrict__ bsums) {
    int i = blockIdx.x * 256 + threadIdx.x;
    if (i < N_NODES) {
        int r = row[i] + bsums[blockIdx.x];
        row[i] = r;
        cursor[i] = r;
    }
    if (i == 0) row[N_NODES] = N_EDGES;
}

__global__ void k_scatter(const int* __restrict__ dst, const int* __restrict__ srcarr,
                          int* __restrict__ cursor, int* __restrict__ adj) {
    int e = blockIdx.x * 256 + threadIdx.x;
    if (e < N_EDGES) {
        int d = dst[e];
        int s = srcarr[e];
        int p = atomicAdd(&cursor[d], 1);
        adj[p] = s;
    }
}

// ---------------- dense (weights-in-registers, no LDS) ----------------

// x = gf @ W_in + b_in.  [50000x64]@[64x32].
// One wave per 16 nodes. Lane l: col c=l&31, k-half h=l>>5 (k in [32h,32h+32)).
// W held in 32 VGPRs/lane; x-row loaded via wave-uniform pointer; half-sum
// combined with one shfl_xor(32); lanes 0..31 store 128B row.
__global__ void k_embed(const float* __restrict__ gf, const float* __restrict__ W,
                        const float* __restrict__ b, float* __restrict__ x) {
    int lane = threadIdx.x & 63;
    int wave = (blockIdx.x * 256 + threadIdx.x) >> 6;
    int c = lane & 31, h = lane >> 5;
    float w[32];
#pragma unroll
    for (int k = 0; k < 32; k++) w[k] = W[(h * 32 + k) * DIM_H + c];
    float bc = b[c];
    int n0 = wave * 16;
#pragma unroll 2
    for (int i = 0; i < 16; i++) {
        int n = n0 + i;
        if (n >= N_NODES) break;
        int nu = __builtin_amdgcn_readfirstlane(n);
        const float4* xr = (const float4*)(gf + (size_t)nu * DIM_IN + h * 32);
        float acc = 0.f;
#pragma unroll
        for (int k4 = 0; k4 < 8; k4++) {
            float4 xv = xr[k4];
            acc += xv.x * w[k4 * 4 + 0];
            acc += xv.y * w[k4 * 4 + 1];
            acc += xv.z * w[k4 * 4 + 2];
            acc += xv.w * w[k4 * 4 + 3];
        }
        acc += __shfl_xor(acc, 32, 64);
        if (lane < 32) x[(size_t)nu * DIM_H + c] = acc + bc;
    }
}

// ff[n][0:128]=fs(n), ff[n][128:256]=fd(n).  [50000x32]@[32x256].
// One wave per 16 nodes. Lane l owns output cols 4l..4l+3; W[:,4l..4l+3] in
// 32 float4 registers (static index, fully unrolled). x-row via wave-uniform
// broadcast loads. Store: 64 lanes x 16B = one contiguous 1KB segment.
// __launch_bounds__(256,1): grant the ~160 VGPRs this needs (R4's default
// 64-VGPR budget spilled w[] to scratch: WRITE 73MB vs 51MB logical).
__global__ __launch_bounds__(256, 1) void k_proj(
    const float* __restrict__ x, const float* __restrict__ Wsrc,
    const float* __restrict__ bsrc, const float* __restrict__ Wdst,
    const float* __restrict__ bdst, float* __restrict__ ff) {
    int lane = threadIdx.x & 63;
    int wave = (blockIdx.x * 256 + threadIdx.x) >> 6;
    int cl = lane & 31;
    const float4* Wb = (lane < 32) ? (const float4*)Wsrc : (const float4*)Wdst;
    const float4* bb = (lane < 32) ? (const float4*)bsrc : (const float4*)bdst;
    float4 w[32];
#pragma unroll
    for (int k = 0; k < 32; k++) w[k] = Wb[k * 32 + cl];
    float4 bias = bb[cl];
    int n0 = wave * 16;
#pragma unroll 2
    for (int i = 0; i < 16; i++) {
        int n = n0 + i;
        if (n >= N_NODES) break;
        int nu = __builtin_amdgcn_readfirstlane(n);
        const float4* xr = (const float4*)(x + (size_t)nu * DIM_H);
        float4 acc = bias;
#pragma unroll
        for (int k4 = 0; k4 < 8; k4++) {
            float4 xv = xr[k4];
#pragma unroll
            for (int j = 0; j < 4; j++) {
                float xk = (j == 0) ? xv.x : (j == 1) ? xv.y : (j == 2) ? xv.z : xv.w;
                float4 wk = w[k4 * 4 + j];
                acc.x += xk * wk.x;
                acc.y += xk * wk.y;
                acc.z += xk * wk.z;
                acc.w += xk * wk.w;
            }
        }
        *(float4*)&ff[(size_t)nu * 256 + lane * 4] = acc;
    }
}

// ---------------- GAT gather ----------------
// One wave per destination node. Lane l: head h=l>>4, float2 slot l of the
// 128-float fs part. ff row: [fs(128) | fd(128)]. Adjacency lane-parallel +
// shfl broadcast; 8 independent neighbor-row loads in flight. Softmax shift
// dropped (shift-invariant; |logits| small). Epilogue fuses head-mean.
__device__ __forceinline__ void edge_acc(float2 f, float2 fdv, float2 a2,
                                         float2& acc, float& den) {
    float tx = f.x + fdv.x; tx = tx > 0.f ? tx : NEG * tx;
    float ty = f.y + fdv.y; ty = ty > 0.f ? ty : NEG * ty;
    float p = tx * a2.x + ty * a2.y;
    p += __shfl_xor(p, 1, 64);
    p += __shfl_xor(p, 2, 64);
    p += __shfl_xor(p, 4, 64);
    p += __shfl_xor(p, 8, 64);
    float w = __expf(p);
    den += w;
    acc.x += w * f.x;
    acc.y += w * f.y;
}

__global__ void k_gather(const float* __restrict__ ff, const float* __restrict__ attn,
                         const int* __restrict__ row, const int* __restrict__ adj,
                         float* __restrict__ xout, int do_relu) {
    int wave = threadIdx.x >> 6;
    int lane = threadIdx.x & 63;
    int n = blockIdx.x * 4 + wave;
    if (n >= N_NODES) return;
    float2 a2 = ((const float2*)attn)[lane];
    const float2* ff2 = (const float2*)ff;
    float2 fdv = ff2[(size_t)n * 128 + 64 + lane];
    float2 acc = {0.f, 0.f};
    float den = 0.f;
    int beg = row[n], end = row[n + 1];
    for (int base = beg; base < end; base += 64) {
        int m = end - base;
        if (m > 64) m = 64;
        int myadj = (lane < m) ? adj[base + lane] : 0;
        int j = 0;
        for (; j + 8 <= m; j += 8) {
            int s0 = __shfl(myadj, j + 0, 64);
            int s1 = __shfl(myadj, j + 1, 64);
            int s2 = __shfl(myadj, j + 2, 64);
            int s3 = __shfl(myadj, j + 3, 64);
            int s4 = __shfl(myadj, j + 4, 64);
            int s5 = __shfl(myadj, j + 5, 64);
            int s6 = __shfl(myadj, j + 6, 64);
            int s7 = __shfl(myadj, j + 7, 64);
            float2 f0 = ff2[(size_t)s0 * 128 + lane];
            float2 f1 = ff2[(size_t)s1 * 128 + lane];
            float2 f2 = ff2[(size_t)s2 * 128 + lane];
            float2 f3 = ff2[(size_t)s3 * 128 + lane];
            float2 f4 = ff2[(size_t)s4 * 128 + lane];
            float2 f5 = ff2[(size_t)s5 * 128 + lane];
            float2 f6 = ff2[(size_t)s6 * 128 + lane];
            float2 f7 = ff2[(size_t)s7 * 128 + lane];
            edge_acc(f0, fdv, a2, acc, den);
            edge_acc(f1, fdv, a2, acc, den);
            edge_acc(f2, fdv, a2, acc, den);
            edge_acc(f3, fdv, a2, acc, den);
            edge_acc(f4, fdv, a2, acc, den);
            edge_acc(f5, fdv, a2, acc, den);
            edge_acc(f6, fdv, a2, acc, den);
            edge_acc(f7, fdv, a2, acc, den);
        }
        for (; j < m; ++j) {
            int s = __shfl(myadj, j, 64);
            float2 f = ff2[(size_t)s * 128 + lane];
            edge_acc(f, fdv, a2, acc, den);
        }
    }
    float inv = den > 0.f ? 1.f / den : 0.f;
    float ox = acc.x * inv, oy = acc.y * inv;
    float vx = ox + __shfl_xor(ox, 16, 64);
    float vy = oy + __shfl_xor(oy, 16, 64);
    vx += __shfl_xor(vx, 32, 64);
    vy += __shfl_xor(vy, 32, 64);
    vx *= 0.25f;
    vy *= 0.25f;
    if (do_relu) {
        vx = vx > 0.f ? vx : 0.f;
        vy = vy > 0.f ? vy : 0.f;
    }
    if (lane < 16) ((float2*)(xout + (size_t)n * 32))[lane] = make_float2(vx, vy);
}

// sum x[n][32] over nodes -> partial[block][32]
__global__ void k_reduce(const float* __restrict__ x, float* __restrict__ partial) {
    int d = threadIdx.x & 31, g = threadIdx.x >> 5;
    float acc = 0.f;
    int stride = gridDim.x * 8;
    for (int n = blockIdx.x * 8 + g; n < N_NODES; n += stride) {
        acc += x[(size_t)n * 32 + d];
    }
    __shared__ float s[256];
    s[threadIdx.x] = acc;
    __syncthreads();
    for (int off = 128; off >= 32; off >>= 1) {
        if (threadIdx.x < off) s[threadIdx.x] += s[threadIdx.x + off];
        __syncthreads();
    }
    if (threadIdx.x < 32) partial[blockIdx.x * 32 + threadIdx.x] = s[threadIdx.x];
}

__global__ void k_final(const float* __restrict__ partial, const float* __restrict__ Wh1,
                        const float* __restrict__ bh1, const float* __restrict__ Wh2,
                        const float* __restrict__ bh2, float* __restrict__ out) {
    __shared__ float gv[32], gh[32], lg[16];
    int t = threadIdx.x;
    if (t < 32) {
        float s = 0.f;
        for (int b = 0; b < 256; b++) s += partial[b * 32 + t];
        gv[t] = s * (1.f / (float)N_NODES);
    }
    __syncthreads();
    if (t < 32) {
        float s = bh1[t];
        for (int d = 0; d < 32; d++) s += gv[d] * Wh1[d * 32 + t];
        gh[t] = s > 0.f ? s : 0.f;
    }
    __syncthreads();
    if (t < NCLS) {
        float s = bh2[t];
        for (int j = 0; j < 32; j++) s += gh[j] * Wh2[j * NCLS + t];
        lg[t] = s;
    }
    __syncthreads();
    if (t == 0) {
        float m = lg[0];
        for (int c = 1; c < NCLS; c++) m = fmaxf(m, lg[c]);
        float ex[NCLS], sum = 0.f;
        for (int c = 0; c < NCLS; c++) {
            ex[c] = __expf(lg[c] - m);
            sum += ex[c];
        }
        float inv = 1.f / sum;
        for (int c = 0; c < NCLS; c++) out[c] = ex[c] * inv;
    }
}

extern "C" void kernel_launch(void* const* d_in, const int* in_sizes, int n_in,
                              void* d_out, int out_size, void* d_ws, size_t ws_size,
                              hipStream_t stream) {
    const float* g_feats = (const float*)d_in[0];
    const int* edge_src = (const int*)d_in[1];
    const int* edge_dst = (const int*)d_in[2];
    const float* W_in = (const float*)d_in[3];
    const float* b_in = (const float*)d_in[4];
    const float* W1_src = (const float*)d_in[5];
    const float* b1_src = (const float*)d_in[6];
    const float* W1_dst = (const float*)d_in[7];
    const float* b1_dst = (const float*)d_in[8];
    const float* attn1 = (const float*)d_in[9];
    const float* W2_src = (const float*)d_in[10];
    const float* b2_src = (const float*)d_in[11];
    const float* W2_dst = (const float*)d_in[12];
    const float* b2_dst = (const float*)d_in[13];
    const float* attn2 = (const float*)d_in[14];
    const float* Wh1 = (const float*)d_in[15];
    const float* bh1 = (const float*)d_in[16];
    const float* Wh2 = (const float*)d_in[17];
    const float* bh2 = (const float*)d_in[18];

    // workspace layout
    float* x = (float*)d_ws;                      // N*32
    float* ff = x + (size_t)N_NODES * 32;         // N*256 (fs|fd interleaved)
    float* partial = ff + (size_t)N_NODES * 256;  // 256*32
    int* deg = (int*)(partial + 256 * 32);        // N
    int* row = deg + N_NODES;                     // N+1
    int* cursor = row + N_NODES + 1;              // N
    int* adj = cursor + N_NODES;                  // E (src values, CSR order)
    int* bsums = adj + N_EDGES;                   // NB

    const int EB = (N_EDGES + 255) / 256;
    const int NB = (N_NODES + 255) / 256;  // 196
    const int WB = (N_NODES + 63) / 64;    // 782: 4 waves/block x 16 nodes/wave

    hipMemsetAsync(deg, 0, N_NODES * sizeof(int), stream);
    k_hist<<<EB, 256, 0, stream>>>(edge_dst, deg);
    k_scan_block<<<NB, 256, 0, stream>>>(deg, row, bsums);
    k_scan_sums<<<1, 256, 0, stream>>>(bsums, NB);
    k_scan_add<<<NB, 256, 0, stream>>>(row, cursor, bsums);
    k_scatter<<<EB, 256, 0, stream>>>(edge_dst, edge_src, cursor, adj);

    k_embed<<<WB, 256, 0, stream>>>(g_feats, W_in, b_in, x);

    // layer 1
    k_proj<<<WB, 256, 0, stream>>>(x, W1_src, b1_src, W1_dst, b1_dst, ff);
    k_gather<<<(N_NODES + 3) / 4, 256, 0, stream>>>(ff, attn1, row, adj, x, 1);

    // layer 2
    k_proj<<<WB, 256, 0, stream>>>(x, W2_src, b2_src, W2_dst, b2_dst, ff);
    k_gather<<<(N_NODES + 3) / 4, 256, 0, stream>>>(ff, attn2, row, adj, x, 0);

    k_reduce<<<256, 256, 0, stream>>>(x, partial);
    k_final<<<1, 256, 0, stream>>>(partial, Wh1, bh1, Wh2, bh2, (float*)d_out);
}

// Round 6
// 273.810 us; speedup vs baseline: 3.8435x; 1.1456x over previous
//
#include <hip/hip_runtime.h>
#include <hip/hip_bf16.h>

#define N_NODES 50000
#define N_EDGES 800000
#define DIM_IN 64
#define DIM_H 32
#define HEADS 4
#define NCLS 10
#define NEG 0.2f

// ---------------- CSR build ----------------

__global__ void k_hist(const int* __restrict__ dst, int* __restrict__ deg) {
    int e = blockIdx.x * 256 + threadIdx.x;
    if (e < N_EDGES) atomicAdd(&deg[dst[e]], 1);
}

__global__ void k_scan_block(const int* __restrict__ deg, int* __restrict__ row,
                             int* __restrict__ bsums) {
    __shared__ int s[256];
    int i = blockIdx.x * 256 + threadIdx.x;
    int v = (i < N_NODES) ? deg[i] : 0;
    s[threadIdx.x] = v;
    __syncthreads();
    for (int off = 1; off < 256; off <<= 1) {
        int t = (threadIdx.x >= off) ? s[threadIdx.x - off] : 0;
        __syncthreads();
        s[threadIdx.x] += t;
        __syncthreads();
    }
    if (i < N_NODES) row[i] = s[threadIdx.x] - v;  // exclusive
    if (threadIdx.x == 255) bsums[blockIdx.x] = s[255];
}

__global__ void k_scan_sums(int* __restrict__ bsums, int nb) {
    __shared__ int s[256];
    int v = (threadIdx.x < nb) ? bsums[threadIdx.x] : 0;
    s[threadIdx.x] = v;
    __syncthreads();
    for (int off = 1; off < 256; off <<= 1) {
        int t = (threadIdx.x >= off) ? s[threadIdx.x - off] : 0;
        __syncthreads();
        s[threadIdx.x] += t;
        __syncthreads();
    }
    if (threadIdx.x < nb) bsums[threadIdx.x] = s[threadIdx.x] - v;  // exclusive
}

__global__ void k_scan_add(int* __restrict__ row, int* __restrict__ cursor,
                           const int* __restrict__ bsums) {
    int i = blockIdx.x * 256 + threadIdx.x;
    if (i < N_NODES) {
        int r = row[i] + bsums[blockIdx.x];
        row[i] = r;
        cursor[i] = r;
    }
    if (i == 0) row[N_NODES] = N_EDGES;
}

__global__ void k_scatter(const int* __restrict__ dst, const int* __restrict__ srcarr,
                          int* __restrict__ cursor, int* __restrict__ adj) {
    int e = blockIdx.x * 256 + threadIdx.x;
    if (e < N_EDGES) {
        int d = dst[e];
        int s = srcarr[e];
        int p = atomicAdd(&cursor[d], 1);
        adj[p] = s;
    }
}

// ---------------- helpers ----------------

__device__ __forceinline__ unsigned short f2bf(float v) {  // RTN f32->bf16
    unsigned u = __builtin_bit_cast(unsigned, v);
    u += 0x7FFFu + ((u >> 16) & 1u);
    return (unsigned short)(u >> 16);
}
__device__ __forceinline__ float bf2f(unsigned short h) {
    return __builtin_bit_cast(float, (unsigned)h << 16);
}

// ---------------- dense (weights-in-registers, no LDS) ----------------

// x = gf @ W_in + b_in.  [50000x64]@[64x32].
__global__ void k_embed(const float* __restrict__ gf, const float* __restrict__ W,
                        const float* __restrict__ b, float* __restrict__ x) {
    int lane = threadIdx.x & 63;
    int wave = (blockIdx.x * 256 + threadIdx.x) >> 6;
    int c = lane & 31, h = lane >> 5;
    float w[32];
#pragma unroll
    for (int k = 0; k < 32; k++) w[k] = W[(h * 32 + k) * DIM_H + c];
    float bc = b[c];
    int n0 = wave * 16;
#pragma unroll 2
    for (int i = 0; i < 16; i++) {
        int n = n0 + i;
        if (n >= N_NODES) break;
        int nu = __builtin_amdgcn_readfirstlane(n);
        const float4* xr = (const float4*)(gf + (size_t)nu * DIM_IN + h * 32);
        float acc = 0.f;
#pragma unroll
        for (int k4 = 0; k4 < 8; k4++) {
            float4 xv = xr[k4];
            acc += xv.x * w[k4 * 4 + 0];
            acc += xv.y * w[k4 * 4 + 1];
            acc += xv.z * w[k4 * 4 + 2];
            acc += xv.w * w[k4 * 4 + 3];
        }
        acc += __shfl_xor(acc, 32, 64);
        if (lane < 32) x[(size_t)nu * DIM_H + c] = acc + bc;
    }
}

// fs (bf16) and fd (f32) projections.  [50000x32]@[32x256].
// Lane l owns output cols 4l..4l+3 of [fs|fd]; W[:,4l..4l+3] in 32 float4
// registers. Lanes<32 -> fs as bf16 ushort4 (8B); lanes>=32 -> fd float4.
__global__ __launch_bounds__(256, 1) void k_proj(
    const float* __restrict__ x, const float* __restrict__ Wsrc,
    const float* __restrict__ bsrc, const float* __restrict__ Wdst,
    const float* __restrict__ bdst, unsigned short* __restrict__ fsh,
    float* __restrict__ fd) {
    int lane = threadIdx.x & 63;
    int wave = (blockIdx.x * 256 + threadIdx.x) >> 6;
    int cl = lane & 31;
    const float4* Wb = (lane < 32) ? (const float4*)Wsrc : (const float4*)Wdst;
    const float4* bb = (lane < 32) ? (const float4*)bsrc : (const float4*)bdst;
    float4 w[32];
#pragma unroll
    for (int k = 0; k < 32; k++) w[k] = Wb[k * 32 + cl];
    float4 bias = bb[cl];
    int n0 = wave * 16;
#pragma unroll 2
    for (int i = 0; i < 16; i++) {
        int n = n0 + i;
        if (n >= N_NODES) break;
        int nu = __builtin_amdgcn_readfirstlane(n);
        const float4* xr = (const float4*)(x + (size_t)nu * DIM_H);
        float4 acc = bias;
#pragma unroll
        for (int k4 = 0; k4 < 8; k4++) {
            float4 xv = xr[k4];
#pragma unroll
            for (int j = 0; j < 4; j++) {
                float xk = (j == 0) ? xv.x : (j == 1) ? xv.y : (j == 2) ? xv.z : xv.w;
                float4 wk = w[k4 * 4 + j];
                acc.x += xk * wk.x;
                acc.y += xk * wk.y;
                acc.z += xk * wk.z;
                acc.w += xk * wk.w;
            }
        }
        if (lane < 32) {
            ushort4 o;
            o.x = f2bf(acc.x);
            o.y = f2bf(acc.y);
            o.z = f2bf(acc.z);
            o.w = f2bf(acc.w);
            *(ushort4*)&fsh[(size_t)nu * 128 + cl * 4] = o;
        } else {
            *(float4*)&fd[(size_t)nu * 128 + cl * 4] = acc;
        }
    }
}

// ---------------- GAT gather (2 edges per wave-instruction) ----------------
// One wave per destination node. Lane = (e2=lane>>5 edge parity, sub=lane&31).
// Within 32 lanes: head h=sub>>3, 4 dims per lane (cols h*32+(sub&7)*4..+3).
// fs row: 128 bf16 (256B) -> one ushort4 (8B) per lane. Score reduce: 3
// shfl_xor over the 8 lanes of a head. Halves combined at the end (xor 32);
// head-mean via xor 8,16. Softmax shift dropped (shift-invariant).
__device__ __forceinline__ void pair_acc(ushort4 u, float4 fdv, float4 a4,
                                         float4& acc, float& den, bool valid) {
    float f0 = bf2f(u.x), f1 = bf2f(u.y), f2 = bf2f(u.z), f3 = bf2f(u.w);
    float t0 = f0 + fdv.x; t0 = t0 > 0.f ? t0 : NEG * t0;
    float t1 = f1 + fdv.y; t1 = t1 > 0.f ? t1 : NEG * t1;
    float t2 = f2 + fdv.z; t2 = t2 > 0.f ? t2 : NEG * t2;
    float t3 = f3 + fdv.w; t3 = t3 > 0.f ? t3 : NEG * t3;
    float p = t0 * a4.x + t1 * a4.y + t2 * a4.z + t3 * a4.w;
    p += __shfl_xor(p, 1, 64);
    p += __shfl_xor(p, 2, 64);
    p += __shfl_xor(p, 4, 64);
    float w = __expf(p);
    if (!valid) w = 0.f;
    den += w;
    acc.x += w * f0;
    acc.y += w * f1;
    acc.z += w * f2;
    acc.w += w * f3;
}

__global__ void k_gather(const unsigned short* __restrict__ fsh,
                         const float* __restrict__ fd, const float* __restrict__ attn,
                         const int* __restrict__ row, const int* __restrict__ adj,
                         float* __restrict__ xout, int do_relu) {
    int wave = threadIdx.x >> 6;
    int lane = threadIdx.x & 63;
    int n = blockIdx.x * 4 + wave;
    if (n >= N_NODES) return;
    int sub = lane & 31, e2 = lane >> 5;
    float4 a4 = ((const float4*)attn)[sub];
    float4 fdv = ((const float4*)(fd + (size_t)n * 128))[sub];
    const ushort4* fs4 = (const ushort4*)fsh;  // row stride 32 x ushort4
    float4 acc = {0.f, 0.f, 0.f, 0.f};
    float den = 0.f;
    int beg = row[n], end = row[n + 1];
    for (int base = beg; base < end; base += 64) {
        int m = end - base;
        if (m > 64) m = 64;
        int myadj = (lane < m) ? adj[base + lane] : 0;
        int j = 0;
        for (; j + 8 <= m; j += 8) {  // 4 pairs = 8 edges
            int s0 = __shfl(myadj, j + 0 + e2, 64);
            int s1 = __shfl(myadj, j + 2 + e2, 64);
            int s2 = __shfl(myadj, j + 4 + e2, 64);
            int s3 = __shfl(myadj, j + 6 + e2, 64);
            ushort4 u0 = fs4[(size_t)s0 * 32 + sub];
            ushort4 u1 = fs4[(size_t)s1 * 32 + sub];
            ushort4 u2 = fs4[(size_t)s2 * 32 + sub];
            ushort4 u3 = fs4[(size_t)s3 * 32 + sub];
            pair_acc(u0, fdv, a4, acc, den, true);
            pair_acc(u1, fdv, a4, acc, den, true);
            pair_acc(u2, fdv, a4, acc, den, true);
            pair_acc(u3, fdv, a4, acc, den, true);
        }
        for (; j < m; j += 2) {  // tail pairs (possibly half-valid)
            int idx = j + e2;
            bool valid = idx < m;
            int s = __shfl(myadj, valid ? idx : j, 64);
            ushort4 u = fs4[(size_t)s * 32 + sub];
            pair_acc(u, fdv, a4, acc, den, valid);
        }
    }
    // combine edge-parity halves
    den += __shfl_xor(den, 32, 64);
    acc.x += __shfl_xor(acc.x, 32, 64);
    acc.y += __shfl_xor(acc.y, 32, 64);
    acc.z += __shfl_xor(acc.z, 32, 64);
    acc.w += __shfl_xor(acc.w, 32, 64);
    float inv = den > 0.f ? 1.f / den : 0.f;
    float4 o;
    o.x = acc.x * inv;
    o.y = acc.y * inv;
    o.z = acc.z * inv;
    o.w = acc.w * inv;
    // head mean: sum over sub^8, sub^16 -> every lane has the 4-head sum
    o.x += __shfl_xor(o.x, 8, 64);
    o.y += __shfl_xor(o.y, 8, 64);
    o.z += __shfl_xor(o.z, 8, 64);
    o.w += __shfl_xor(o.w, 8, 64);
    o.x += __shfl_xor(o.x, 16, 64);
    o.y += __shfl_xor(o.y, 16, 64);
    o.z += __shfl_xor(o.z, 16, 64);
    o.w += __shfl_xor(o.w, 16, 64);
    o.x *= 0.25f;
    o.y *= 0.25f;
    o.z *= 0.25f;
    o.w *= 0.25f;
    if (do_relu) {
        o.x = o.x > 0.f ? o.x : 0.f;
        o.y = o.y > 0.f ? o.y : 0.f;
        o.z = o.z > 0.f ? o.z : 0.f;
        o.w = o.w > 0.f ? o.w : 0.f;
    }
    if (lane < 8) ((float4*)(xout + (size_t)n * 32))[lane] = o;
}

// sum x[n][32] over nodes -> partial[block][32]
__global__ void k_reduce(const float* __restrict__ x, float* __restrict__ partial) {
    int d = threadIdx.x & 31, g = threadIdx.x >> 5;
    float acc = 0.f;
    int stride = gridDim.x * 8;
    for (int n = blockIdx.x * 8 + g; n < N_NODES; n += stride) {
        acc += x[(size_t)n * 32 + d];
    }
    __shared__ float s[256];
    s[threadIdx.x] = acc;
    __syncthreads();
    for (int off = 128; off >= 32; off >>= 1) {
        if (threadIdx.x < off) s[threadIdx.x] += s[threadIdx.x + off];
        __syncthreads();
    }
    if (threadIdx.x < 32) partial[blockIdx.x * 32 + threadIdx.x] = s[threadIdx.x];
}

__global__ void k_final(const float* __restrict__ partial, const float* __restrict__ Wh1,
                        const float* __restrict__ bh1, const float* __restrict__ Wh2,
                        const float* __restrict__ bh2, float* __restrict__ out) {
    __shared__ float gv[32], gh[32], lg[16];
    int t = threadIdx.x;
    if (t < 32) {
        float s = 0.f;
        for (int b = 0; b < 256; b++) s += partial[b * 32 + t];
        gv[t] = s * (1.f / (float)N_NODES);
    }
    __syncthreads();
    if (t < 32) {
        float s = bh1[t];
        for (int d = 0; d < 32; d++) s += gv[d] * Wh1[d * 32 + t];
        gh[t] = s > 0.f ? s : 0.f;
    }
    __syncthreads();
    if (t < NCLS) {
        float s = bh2[t];
        for (int j = 0; j < 32; j++) s += gh[j] * Wh2[j * NCLS + t];
        lg[t] = s;
    }
    __syncthreads();
    if (t == 0) {
        float m = lg[0];
        for (int c = 1; c < NCLS; c++) m = fmaxf(m, lg[c]);
        float ex[NCLS], sum = 0.f;
        for (int c = 0; c < NCLS; c++) {
            ex[c] = __expf(lg[c] - m);
            sum += ex[c];
        }
        float inv = 1.f / sum;
        for (int c = 0; c < NCLS; c++) out[c] = ex[c] * inv;
    }
}

extern "C" void kernel_launch(void* const* d_in, const int* in_sizes, int n_in,
                              void* d_out, int out_size, void* d_ws, size_t ws_size,
                              hipStream_t stream) {
    const float* g_feats = (const float*)d_in[0];
    const int* edge_src = (const int*)d_in[1];
    const int* edge_dst = (const int*)d_in[2];
    const float* W_in = (const float*)d_in[3];
    const float* b_in = (const float*)d_in[4];
    const float* W1_src = (const float*)d_in[5];
    const float* b1_src = (const float*)d_in[6];
    const float* W1_dst = (const float*)d_in[7];
    const float* b1_dst = (const float*)d_in[8];
    const float* attn1 = (const float*)d_in[9];
    const float* W2_src = (const float*)d_in[10];
    const float* b2_src = (const float*)d_in[11];
    const float* W2_dst = (const float*)d_in[12];
    const float* b2_dst = (const float*)d_in[13];
    const float* attn2 = (const float*)d_in[14];
    const float* Wh1 = (const float*)d_in[15];
    const float* bh1 = (const float*)d_in[16];
    const float* Wh2 = (const float*)d_in[17];
    const float* bh2 = (const float*)d_in[18];

    // workspace layout
    float* x = (float*)d_ws;                         // N*32 f32
    unsigned short* fsh = (unsigned short*)(x + (size_t)N_NODES * 32);  // N*128 bf16
    float* fd = (float*)(fsh + (size_t)N_NODES * 128);                  // N*128 f32
    float* partial = fd + (size_t)N_NODES * 128;     // 256*32
    int* deg = (int*)(partial + 256 * 32);           // N
    int* row = deg + N_NODES;                        // N+1
    int* cursor = row + N_NODES + 1;                 // N
    int* adj = cursor + N_NODES;                     // E (src values, CSR order)
    int* bsums = adj + N_EDGES;                      // NB

    const int EB = (N_EDGES + 255) / 256;
    const int NB = (N_NODES + 255) / 256;  // 196
    const int WB = (N_NODES + 63) / 64;    // 782: 4 waves/block x 16 nodes/wave

    hipMemsetAsync(deg, 0, N_NODES * sizeof(int), stream);
    k_hist<<<EB, 256, 0, stream>>>(edge_dst, deg);
    k_scan_block<<<NB, 256, 0, stream>>>(deg, row, bsums);
    k_scan_sums<<<1, 256, 0, stream>>>(bsums, NB);
    k_scan_add<<<NB, 256, 0, stream>>>(row, cursor, bsums);
    k_scatter<<<EB, 256, 0, stream>>>(edge_dst, edge_src, cursor, adj);

    k_embed<<<WB, 256, 0, stream>>>(g_feats, W_in, b_in, x);

    // layer 1
    k_proj<<<WB, 256, 0, stream>>>(x, W1_src, b1_src, W1_dst, b1_dst, fsh, fd);
    k_gather<<<(N_NODES + 3) / 4, 256, 0, stream>>>(fsh, fd, attn1, row, adj, x, 1);

    // layer 2
    k_proj<<<WB, 256, 0, stream>>>(x, W2_src, b2_src, W2_dst, b2_dst, fsh, fd);
    k_gather<<<(N_NODES + 3) / 4, 256, 0, stream>>>(fsh, fd, attn2, row, adj, x, 0);

    k_reduce<<<256, 256, 0, stream>>>(x, partial);
    k_final<<<1, 256, 0, stream>>>(partial, Wh1, bh1, Wh2, bh2, (float*)d_out);
}

// Round 7
// 239.978 us; speedup vs baseline: 4.3853x; 1.1410x over previous
//
#include <hip/hip_runtime.h>
#include <hip/hip_bf16.h>

#define N_NODES 50000
#define N_EDGES 800000
#define DIM_IN 64
#define DIM_H 32
#define HEADS 4
#define NCLS 10
#define NEG 0.2f
#define NBUCK 196  // ceil(50000/256) buckets of 256 dst nodes

// ---------------- CSR build (binned, single-writer adj regions) ----------------

// bucket histogram: LDS-aggregated
__global__ void k_bhist(const int* __restrict__ dst, int* __restrict__ bh) {
    __shared__ int lh[NBUCK];
    for (int i = threadIdx.x; i < NBUCK; i += 256) lh[i] = 0;
    __syncthreads();
    int base = blockIdx.x * 1024 + threadIdx.x;
#pragma unroll
    for (int r = 0; r < 4; r++) {
        int e = base + r * 256;
        if (e < N_EDGES) atomicAdd(&lh[dst[e] >> 8], 1);
    }
    __syncthreads();
    for (int i = threadIdx.x; i < NBUCK; i += 256) {
        int c = lh[i];
        if (c) atomicAdd(&bh[i], c);
    }
}

// exclusive scan of bucket sizes -> bbase[NBUCK+1]; gcur = running cursors
__global__ void k_bscan(const int* __restrict__ bh, int* __restrict__ bbase,
                        int* __restrict__ gcur) {
    __shared__ int s[256];
    int t = threadIdx.x;
    int v = (t < NBUCK) ? bh[t] : 0;
    s[t] = v;
    __syncthreads();
    for (int off = 1; off < 256; off <<= 1) {
        int u = (t >= off) ? s[t - off] : 0;
        __syncthreads();
        s[t] += u;
        __syncthreads();
    }
    int excl = s[t] - v;
    if (t < NBUCK) {
        bbase[t] = excl;
        gcur[t] = excl;
    }
    if (t == 0) bbase[NBUCK] = N_EDGES;
}

// bin edges into bucket-ordered staging as packed (src | dlocal<<16).
// Per block: LDS count -> one chunk-reservation atomic per bucket -> chunked
// writes (good line locality, ~2x logical bytes instead of 16x).
__global__ void k_bin(const int* __restrict__ src, const int* __restrict__ dst,
                      int* __restrict__ gcur, unsigned* __restrict__ stage) {
    __shared__ int lh[NBUCK], chunk[NBUCK];
    int t = threadIdx.x;
    for (int i = t; i < NBUCK; i += 256) lh[i] = 0;
    __syncthreads();
    int e0 = blockIdx.x * 4096;
    unsigned pk[16];
    int bk[16];
#pragma unroll
    for (int r = 0; r < 16; r++) {
        int e = e0 + r * 256 + t;
        bool ok = e < N_EDGES;
        int s = ok ? src[e] : 0;
        int d = ok ? dst[e] : 0;
        bk[r] = ok ? (d >> 8) : -1;
        pk[r] = (unsigned)s | ((unsigned)(d & 255) << 16);
        if (ok) atomicAdd(&lh[bk[r]], 1);
    }
    __syncthreads();
    for (int i = t; i < NBUCK; i += 256) {
        int c = lh[i];
        chunk[i] = c ? atomicAdd(&gcur[i], c) : 0;
        lh[i] = 0;  // reuse as local cursor
    }
    __syncthreads();
#pragma unroll
    for (int r = 0; r < 16; r++) {
        if (bk[r] >= 0) {
            int lp = atomicAdd(&lh[bk[r]], 1);
            stage[chunk[bk[r]] + lp] = pk[r];
        }
    }
}

// one workgroup per bucket: local hist+scan -> row[]; scatter src into the
// bucket's private contiguous adj region (single XCD writes each line).
__global__ void k_csr(const unsigned* __restrict__ stage, const int* __restrict__ bbase,
                      int* __restrict__ row, int* __restrict__ adj) {
    __shared__ int lcnt[256], lcur[256], sc[256];
    int b = blockIdx.x, t = threadIdx.x;
    int s0 = bbase[b], s1 = bbase[b + 1];
    lcnt[t] = 0;
    __syncthreads();
    for (int i = s0 + t; i < s1; i += 256) atomicAdd(&lcnt[stage[i] >> 16], 1);
    __syncthreads();
    int v = lcnt[t];
    sc[t] = v;
    __syncthreads();
    for (int off = 1; off < 256; off <<= 1) {
        int u = (t >= off) ? sc[t - off] : 0;
        __syncthreads();
        sc[t] += u;
        __syncthreads();
    }
    int excl = sc[t] - v;
    int n = b * 256 + t;
    if (n < N_NODES) row[n] = s0 + excl;
    if (b == NBUCK - 1 && t == 0) row[N_NODES] = N_EDGES;
    lcur[t] = s0 + excl;
    __syncthreads();
    for (int i = s0 + t; i < s1; i += 256) {
        unsigned p = stage[i];
        int pos = atomicAdd(&lcur[p >> 16], 1);
        adj[pos] = (int)(p & 0xFFFFu);
    }
}

// ---------------- helpers ----------------

__device__ __forceinline__ unsigned short f2bf(float v) {  // RTN f32->bf16
    unsigned u = __builtin_bit_cast(unsigned, v);
    u += 0x7FFFu + ((u >> 16) & 1u);
    return (unsigned short)(u >> 16);
}
__device__ __forceinline__ float bf2f(unsigned short h) {
    return __builtin_bit_cast(float, (unsigned)h << 16);
}

// ---------------- dense (weights-in-registers, no LDS) ----------------

// x = gf @ W_in + b_in.  [50000x64]@[64x32].
__global__ void k_embed(const float* __restrict__ gf, const float* __restrict__ W,
                        const float* __restrict__ b, float* __restrict__ x) {
    int lane = threadIdx.x & 63;
    int wave = (blockIdx.x * 256 + threadIdx.x) >> 6;
    int c = lane & 31, h = lane >> 5;
    float w[32];
#pragma unroll
    for (int k = 0; k < 32; k++) w[k] = W[(h * 32 + k) * DIM_H + c];
    float bc = b[c];
    int n0 = wave * 16;
#pragma unroll 2
    for (int i = 0; i < 16; i++) {
        int n = n0 + i;
        if (n >= N_NODES) break;
        int nu = __builtin_amdgcn_readfirstlane(n);
        const float4* xr = (const float4*)(gf + (size_t)nu * DIM_IN + h * 32);
        float acc = 0.f;
#pragma unroll
        for (int k4 = 0; k4 < 8; k4++) {
            float4 xv = xr[k4];
            acc += xv.x * w[k4 * 4 + 0];
            acc += xv.y * w[k4 * 4 + 1];
            acc += xv.z * w[k4 * 4 + 2];
            acc += xv.w * w[k4 * 4 + 3];
        }
        acc += __shfl_xor(acc, 32, 64);
        if (lane < 32) x[(size_t)nu * DIM_H + c] = acc + bc;
    }
}

// fs (bf16) and fd (f32) projections.  [50000x32]@[32x256].
__global__ __launch_bounds__(256, 1) void k_proj(
    const float* __restrict__ x, const float* __restrict__ Wsrc,
    const float* __restrict__ bsrc, const float* __restrict__ Wdst,
    const float* __restrict__ bdst, unsigned short* __restrict__ fsh,
    float* __restrict__ fd) {
    int lane = threadIdx.x & 63;
    int wave = (blockIdx.x * 256 + threadIdx.x) >> 6;
    int cl = lane & 31;
    const float4* Wb = (lane < 32) ? (const float4*)Wsrc : (const float4*)Wdst;
    const float4* bb = (lane < 32) ? (const float4*)bsrc : (const float4*)bdst;
    float4 w[32];
#pragma unroll
    for (int k = 0; k < 32; k++) w[k] = Wb[k * 32 + cl];
    float4 bias = bb[cl];
    int n0 = wave * 16;
#pragma unroll 2
    for (int i = 0; i < 16; i++) {
        int n = n0 + i;
        if (n >= N_NODES) break;
        int nu = __builtin_amdgcn_readfirstlane(n);
        const float4* xr = (const float4*)(x + (size_t)nu * DIM_H);
        float4 acc = bias;
#pragma unroll
        for (int k4 = 0; k4 < 8; k4++) {
            float4 xv = xr[k4];
#pragma unroll
            for (int j = 0; j < 4; j++) {
                float xk = (j == 0) ? xv.x : (j == 1) ? xv.y : (j == 2) ? xv.z : xv.w;
                float4 wk = w[k4 * 4 + j];
                acc.x += xk * wk.x;
                acc.y += xk * wk.y;
                acc.z += xk * wk.z;
                acc.w += xk * wk.w;
            }
        }
        if (lane < 32) {
            ushort4 o;
            o.x = f2bf(acc.x);
            o.y = f2bf(acc.y);
            o.z = f2bf(acc.z);
            o.w = f2bf(acc.w);
            *(ushort4*)&fsh[(size_t)nu * 128 + cl * 4] = o;
        } else {
            *(float4*)&fd[(size_t)nu * 128 + cl * 4] = acc;
        }
    }
}

// ---------------- GAT gather (2 edges per wave-instruction) ----------------
__device__ __forceinline__ void pair_acc(ushort4 u, float4 fdv, float4 a4,
                                         float4& acc, float& den, bool valid) {
    float f0 = bf2f(u.x), f1 = bf2f(u.y), f2 = bf2f(u.z), f3 = bf2f(u.w);
    float t0 = f0 + fdv.x; t0 = t0 > 0.f ? t0 : NEG * t0;
    float t1 = f1 + fdv.y; t1 = t1 > 0.f ? t1 : NEG * t1;
    float t2 = f2 + fdv.z; t2 = t2 > 0.f ? t2 : NEG * t2;
    float t3 = f3 + fdv.w; t3 = t3 > 0.f ? t3 : NEG * t3;
    float p = t0 * a4.x + t1 * a4.y + t2 * a4.z + t3 * a4.w;
    p += __shfl_xor(p, 1, 64);
    p += __shfl_xor(p, 2, 64);
    p += __shfl_xor(p, 4, 64);
    float w = __expf(p);
    if (!valid) w = 0.f;
    den += w;
    acc.x += w * f0;
    acc.y += w * f1;
    acc.z += w * f2;
    acc.w += w * f3;
}

__global__ void k_gather(const unsigned short* __restrict__ fsh,
                         const float* __restrict__ fd, const float* __restrict__ attn,
                         const int* __restrict__ row, const int* __restrict__ adj,
                         float* __restrict__ xout, int do_relu) {
    int wave = threadIdx.x >> 6;
    int lane = threadIdx.x & 63;
    int n = blockIdx.x * 4 + wave;
    if (n >= N_NODES) return;
    int sub = lane & 31, e2 = lane >> 5;
    float4 a4 = ((const float4*)attn)[sub];
    float4 fdv = ((const float4*)(fd + (size_t)n * 128))[sub];
    const ushort4* fs4 = (const ushort4*)fsh;  // row stride 32 x ushort4
    float4 acc = {0.f, 0.f, 0.f, 0.f};
    float den = 0.f;
    int beg = row[n], end = row[n + 1];
    for (int base = beg; base < end; base += 64) {
        int m = end - base;
        if (m > 64) m = 64;
        int myadj = (lane < m) ? adj[base + lane] : 0;
        int j = 0;
        for (; j + 8 <= m; j += 8) {  // 4 pairs = 8 edges
            int s0 = __shfl(myadj, j + 0 + e2, 64);
            int s1 = __shfl(myadj, j + 2 + e2, 64);
            int s2 = __shfl(myadj, j + 4 + e2, 64);
            int s3 = __shfl(myadj, j + 6 + e2, 64);
            ushort4 u0 = fs4[(size_t)s0 * 32 + sub];
            ushort4 u1 = fs4[(size_t)s1 * 32 + sub];
            ushort4 u2 = fs4[(size_t)s2 * 32 + sub];
            ushort4 u3 = fs4[(size_t)s3 * 32 + sub];
            pair_acc(u0, fdv, a4, acc, den, true);
            pair_acc(u1, fdv, a4, acc, den, true);
            pair_acc(u2, fdv, a4, acc, den, true);
            pair_acc(u3, fdv, a4, acc, den, true);
        }
        for (; j < m; j += 2) {  // tail pairs (possibly half-valid)
            int idx = j + e2;
            bool valid = idx < m;
            int s = __shfl(myadj, valid ? idx : j, 64);
            ushort4 u = fs4[(size_t)s * 32 + sub];
            pair_acc(u, fdv, a4, acc, den, valid);
        }
    }
    den += __shfl_xor(den, 32, 64);
    acc.x += __shfl_xor(acc.x, 32, 64);
    acc.y += __shfl_xor(acc.y, 32, 64);
    acc.z += __shfl_xor(acc.z, 32, 64);
    acc.w += __shfl_xor(acc.w, 32, 64);
    float inv = den > 0.f ? 1.f / den : 0.f;
    float4 o;
    o.x = acc.x * inv;
    o.y = acc.y * inv;
    o.z = acc.z * inv;
    o.w = acc.w * inv;
    o.x += __shfl_xor(o.x, 8, 64);
    o.y += __shfl_xor(o.y, 8, 64);
    o.z += __shfl_xor(o.z, 8, 64);
    o.w += __shfl_xor(o.w, 8, 64);
    o.x += __shfl_xor(o.x, 16, 64);
    o.y += __shfl_xor(o.y, 16, 64);
    o.z += __shfl_xor(o.z, 16, 64);
    o.w += __shfl_xor(o.w, 16, 64);
    o.x *= 0.25f;
    o.y *= 0.25f;
    o.z *= 0.25f;
    o.w *= 0.25f;
    if (do_relu) {
        o.x = o.x > 0.f ? o.x : 0.f;
        o.y = o.y > 0.f ? o.y : 0.f;
        o.z = o.z > 0.f ? o.z : 0.f;
        o.w = o.w > 0.f ? o.w : 0.f;
    }
    if (lane < 8) ((float4*)(xout + (size_t)n * 32))[lane] = o;
}

// sum x[n][32] over nodes -> partial[block][32]
__global__ void k_reduce(const float* __restrict__ x, float* __restrict__ partial) {
    int d = threadIdx.x & 31, g = threadIdx.x >> 5;
    float acc = 0.f;
    int stride = gridDim.x * 8;
    for (int n = blockIdx.x * 8 + g; n < N_NODES; n += stride) {
        acc += x[(size_t)n * 32 + d];
    }
    __shared__ float s[256];
    s[threadIdx.x] = acc;
    __syncthreads();
    for (int off = 128; off >= 32; off >>= 1) {
        if (threadIdx.x < off) s[threadIdx.x] += s[threadIdx.x + off];
        __syncthreads();
    }
    if (threadIdx.x < 32) partial[blockIdx.x * 32 + threadIdx.x] = s[threadIdx.x];
}

__global__ void k_final(const float* __restrict__ partial, const float* __restrict__ Wh1,
                        const float* __restrict__ bh1, const float* __restrict__ Wh2,
                        const float* __restrict__ bh2, float* __restrict__ out) {
    __shared__ float gv[32], gh[32], lg[16];
    int t = threadIdx.x;
    if (t < 32) {
        float s = 0.f;
        for (int b = 0; b < 256; b++) s += partial[b * 32 + t];
        gv[t] = s * (1.f / (float)N_NODES);
    }
    __syncthreads();
    if (t < 32) {
        float s = bh1[t];
        for (int d = 0; d < 32; d++) s += gv[d] * Wh1[d * 32 + t];
        gh[t] = s > 0.f ? s : 0.f;
    }
    __syncthreads();
    if (t < NCLS) {
        float s = bh2[t];
        for (int j = 0; j < 32; j++) s += gh[j] * Wh2[j * NCLS + t];
        lg[t] = s;
    }
    __syncthreads();
    if (t == 0) {
        float m = lg[0];
        for (int c = 1; c < NCLS; c++) m = fmaxf(m, lg[c]);
        float ex[NCLS], sum = 0.f;
        for (int c = 0; c < NCLS; c++) {
            ex[c] = __expf(lg[c] - m);
            sum += ex[c];
        }
        float inv = 1.f / sum;
        for (int c = 0; c < NCLS; c++) out[c] = ex[c] * inv;
    }
}

extern "C" void kernel_launch(void* const* d_in, const int* in_sizes, int n_in,
                              void* d_out, int out_size, void* d_ws, size_t ws_size,
                              hipStream_t stream) {
    const float* g_feats = (const float*)d_in[0];
    const int* edge_src = (const int*)d_in[1];
    const int* edge_dst = (const int*)d_in[2];
    const float* W_in = (const float*)d_in[3];
    const float* b_in = (const float*)d_in[4];
    const float* W1_src = (const float*)d_in[5];
    const float* b1_src = (const float*)d_in[6];
    const float* W1_dst = (const float*)d_in[7];
    const float* b1_dst = (const float*)d_in[8];
    const float* attn1 = (const float*)d_in[9];
    const float* W2_src = (const float*)d_in[10];
    const float* b2_src = (const float*)d_in[11];
    const float* W2_dst = (const float*)d_in[12];
    const float* b2_dst = (const float*)d_in[13];
    const float* attn2 = (const float*)d_in[14];
    const float* Wh1 = (const float*)d_in[15];
    const float* bh1 = (const float*)d_in[16];
    const float* Wh2 = (const float*)d_in[17];
    const float* bh2 = (const float*)d_in[18];

    // workspace layout
    float* x = (float*)d_ws;                                            // N*32 f32
    unsigned short* fsh = (unsigned short*)(x + (size_t)N_NODES * 32);  // N*128 bf16
    float* fd = (float*)(fsh + (size_t)N_NODES * 128);                  // N*128 f32
    float* partial = fd + (size_t)N_NODES * 128;                        // 256*32
    int* row = (int*)(partial + 256 * 32);                              // N+1
    int* bh = row + N_NODES + 1;                                        // NBUCK
    int* bbase = bh + NBUCK;                                            // NBUCK+1
    int* gcur = bbase + NBUCK + 1;                                      // NBUCK
    unsigned* stage = (unsigned*)(gcur + NBUCK);                        // E
    int* adj = (int*)(stage + N_EDGES);                                 // E

    const int WB = (N_NODES + 63) / 64;  // 782: 4 waves/block x 16 nodes/wave

    // CSR build (binned)
    hipMemsetAsync(bh, 0, NBUCK * sizeof(int), stream);
    k_bhist<<<(N_EDGES + 1023) / 1024, 256, 0, stream>>>(edge_dst, bh);
    k_bscan<<<1, 256, 0, stream>>>(bh, bbase, gcur);
    k_bin<<<(N_EDGES + 4095) / 4096, 256, 0, stream>>>(edge_src, edge_dst, gcur, stage);
    k_csr<<<NBUCK, 256, 0, stream>>>(stage, bbase, row, adj);

    k_embed<<<WB, 256, 0, stream>>>(g_feats, W_in, b_in, x);

    // layer 1
    k_proj<<<WB, 256, 0, stream>>>(x, W1_src, b1_src, W1_dst, b1_dst, fsh, fd);
    k_gather<<<(N_NODES + 3) / 4, 256, 0, stream>>>(fsh, fd, attn1, row, adj, x, 1);

    // layer 2
    k_proj<<<WB, 256, 0, stream>>>(x, W2_src, b2_src, W2_dst, b2_dst, fsh, fd);
    k_gather<<<(N_NODES + 3) / 4, 256, 0, stream>>>(fsh, fd, attn2, row, adj, x, 0);

    k_reduce<<<256, 256, 0, stream>>>(x, partial);
    k_final<<<1, 256, 0, stream>>>(partial, Wh1, bh1, Wh2, bh2, (float*)d_out);
}